// Round 5
// baseline (1026.726 us; speedup 1.0000x reference)
//
#include <hip/hip_runtime.h>
#include <hip/hip_bf16.h>
#include <math.h>

// Problem constants
#define E_ 8
#define D_ 2048
#define I_ 4096
#define TOPK_ 2
#define N_ 4096
#define NPAIR (N_*TOPK_)
#define PADMAX 10240
#define MAXTB256 40

typedef __attribute__((ext_vector_type(8))) short s8v;
typedef __attribute__((ext_vector_type(8))) unsigned short us8;
typedef __attribute__((ext_vector_type(4))) float f32x4;
typedef const __attribute__((address_space(1))) void* gvp;
typedef __attribute__((address_space(3))) void* lvp;

__device__ __forceinline__ unsigned short f2bf(float f) {
  union { float f; unsigned int u; } c; c.f = f;
  unsigned int u = c.u;
  u += 0x7fffu + ((u >> 16) & 1u);
  return (unsigned short)(u >> 16);
}

// ---------------- Routing ----------------
__global__ void route_kernel(const int* __restrict__ idx, const float* __restrict__ ew,
                             int pad,
                             int* cnt, int* offs, int* tb, int* ntb,
                             int* perm, float* wgt)
{
  __shared__ int scnt[E_], soff[E_ + 1], scur[E_];
  int t = threadIdx.x;
  if (t < E_) scnt[t] = 0;
  __syncthreads();
  for (int p = t; p < NPAIR; p += blockDim.x) atomicAdd(&scnt[idx[p]], 1);
  __syncthreads();
  if (t == 0) {
    int o = 0;
    for (int e = 0; e < E_; e++) {
      soff[e] = o; scur[e] = o;
      o += ((scnt[e] + pad - 1) / pad) * pad;
    }
    soff[E_] = o;
    int T = 0;
    for (int e = 0; e < E_; e++) {
      int nb = (scnt[e] + pad - 1) / pad;
      for (int rb = 0; rb < nb; rb++) tb[T++] = (e << 16) | rb;
    }
    *ntb = T;
    for (int e = 0; e < E_; e++) { cnt[e] = scnt[e]; offs[e] = soff[e]; }
    offs[E_] = o;
  }
  __syncthreads();
  for (int e = 0; e < E_; e++) {
    int start = soff[e] + scnt[e], end = soff[e + 1];
    for (int s = start + t; s < end; s += blockDim.x) { perm[s] = -1; wgt[s] = 0.f; }
  }
  __syncthreads();
  for (int p = t; p < NPAIR; p += blockDim.x) {
    int e = idx[p];
    int pos = atomicAdd(&scur[e], 1);
    perm[pos] = p / TOPK_;
    wgt[pos]  = ew[p];
  }
}

// ---------------- x: fp32 -> bf16 ----------------
__global__ __launch_bounds__(256)
void cvt8_kernel(const float* __restrict__ src, unsigned short* __restrict__ dst)
{
  size_t i = ((size_t)blockIdx.x * 256 + threadIdx.x) * 8;
  float4 a = *(const float4*)(src + i);
  float4 b = *(const float4*)(src + i + 4);
  us8 o;
  o[0]=f2bf(a.x); o[1]=f2bf(a.y); o[2]=f2bf(a.z); o[3]=f2bf(a.w);
  o[4]=f2bf(b.x); o[5]=f2bf(b.y); o[6]=f2bf(b.z); o[7]=f2bf(b.w);
  *(us8*)(dst + i) = o;
}

// =================== 8-phase 256-tile grouped GEMM machinery ===================
// LDS: smem[65536] ushort = 128 KB. A slabs [2buf][2kh][128vrow][64elem] at 0,
// B slabs same at 32768. vrow v packs rows 2v,2v+1; 16B-chunk at position
// p = c ^ (v&7), logical chunk c = (r&1)*4 + kc.
// A staged via global_load_lds (pre-swizzled gather source);
// B staged via reg: fp32 global loads (2 phases early) -> f2bf -> ds_write_b128.
#define A_SLAB(P,KH) (((P)*2+(KH))*8192)
#define B_SLAB(P,KH) (32768 + ((P)*2+(KH))*8192)

#define SB  __builtin_amdgcn_sched_barrier(0)
#define BARR __builtin_amdgcn_s_barrier()
#define VMW(N) asm volatile("s_waitcnt vmcnt(" #N ")" ::: "memory")
#define LGK asm volatile("s_waitcnt lgkmcnt(0)" ::: "memory")
#define PRIO1 __builtin_amdgcn_s_setprio(1)
#define PRIO0 __builtin_amdgcn_s_setprio(0)

#define LOAD_A(P,KH,MH) { \
  const unsigned short* ap_ = &smem[A_SLAB(P,KH) + aBase + (MH)*2048]; \
  af[0] = *(const s8v*)(ap_);      af[1] = *(const s8v*)(ap_+512); \
  af[2] = *(const s8v*)(ap_+1024); af[3] = *(const s8v*)(ap_+1536); }

#define LOAD_B(P,KH) { \
  const unsigned short* bp_ = &smem[B_SLAB(P,KH) + bBase]; \
  bf[0] = *(const s8v*)(bp_);      bf[1] = *(const s8v*)(bp_+512); \
  bf[2] = *(const s8v*)(bp_+1024); bf[3] = *(const s8v*)(bp_+1536); }

#define STAGE_A(T,KH,P) { \
  __builtin_amdgcn_global_load_lds((gvp)(aptr0 + (T)*64 + (KH)*32), (lvp)(&smem[A_SLAB(P,KH) + (w*2+0)*512]), 16, 0, 0); \
  __builtin_amdgcn_global_load_lds((gvp)(aptr1 + (T)*64 + (KH)*32), (lvp)(&smem[A_SLAB(P,KH) + (w*2+1)*512]), 16, 0, 0); }

// issue 4x dwordx4 fp32 loads for one B kh-slab into xq[Q] (Q is a literal 0/1)
#define ISSUE_B(T,KH,Q) { \
  int o_ = (T)*64 + (KH)*32; \
  xq[Q][0] = *(const float4*)(bsrc0 + o_); xq[Q][1] = *(const float4*)(bsrc0 + o_ + 4); \
  xq[Q][2] = *(const float4*)(bsrc1 + o_); xq[Q][3] = *(const float4*)(bsrc1 + o_ + 4); }

// convert xq[Q] -> bf16, write to slab (linear, matches gl_lds dest layout)
#define CVT_WRITE(Q,P,KH) { \
  us8 o0_, o1_; \
  o0_[0]=f2bf(xq[Q][0].x); o0_[1]=f2bf(xq[Q][0].y); o0_[2]=f2bf(xq[Q][0].z); o0_[3]=f2bf(xq[Q][0].w); \
  o0_[4]=f2bf(xq[Q][1].x); o0_[5]=f2bf(xq[Q][1].y); o0_[6]=f2bf(xq[Q][1].z); o0_[7]=f2bf(xq[Q][1].w); \
  o1_[0]=f2bf(xq[Q][2].x); o1_[1]=f2bf(xq[Q][2].y); o1_[2]=f2bf(xq[Q][2].z); o1_[3]=f2bf(xq[Q][2].w); \
  o1_[4]=f2bf(xq[Q][3].x); o1_[5]=f2bf(xq[Q][3].y); o1_[6]=f2bf(xq[Q][3].z); o1_[7]=f2bf(xq[Q][3].w); \
  *(us8*)(&smem[B_SLAB(P,KH) + (w*2+0)*512 + lane*8]) = o0_; \
  *(us8*)(&smem[B_SLAB(P,KH) + (w*2+1)*512 + lane*8]) = o1_; }

#define MFMA16(MH) { \
  _Pragma("unroll") for (int m_ = 0; m_ < 4; m_++) \
    _Pragma("unroll") for (int n_ = 0; n_ < 4; n_++) \
      acc[(MH)*4+m_][n_] = __builtin_amdgcn_mfma_f32_16x16x32_bf16(af[m_], bf[n_], acc[(MH)*4+m_][n_], 0, 0, 0); }

// 4 phases per K-tile. Steady-state per-wave VMEM queue at each VMW(6):
//  p1: [A(T,kh1):2*, B(T+1,kh0):4*, A(T+1,kh1):2, B(T+1,kh1):4] -> drain *
//  p3: [A(T+1,kh1):2*, B(T+1,kh1):4*, A(T+2,kh0):2, B(T+2,kh0):4] -> drain *
// Every drained slab has >=1 barrier before any wave reads it.
#define TILE_PHASES(T, P, Pn, NT_) { \
  int tn1_ = (T)+1 < (NT_) ? (T)+1 : (NT_)-1; \
  int tn2_ = (T)+2 < (NT_) ? (T)+2 : (NT_)-1; \
  /* p0 */ \
  LOAD_B(P,0); LOAD_A(P,0,0); \
  STAGE_A(tn1_, 1, Pn); \
  SB; BARR; LGK; SB; \
  PRIO1; MFMA16(0); PRIO0; SB; BARR; SB; \
  /* p1 */ \
  LOAD_A(P,0,1); \
  ISSUE_B(tn1_, 1, 1); \
  VMW(6); SB; \
  CVT_WRITE(0, Pn, 0); \
  SB; BARR; LGK; SB; \
  PRIO1; MFMA16(1); PRIO0; SB; BARR; SB; \
  /* p2 */ \
  LOAD_B(P,1); LOAD_A(P,1,0); \
  STAGE_A(tn2_, 0, P); \
  SB; BARR; LGK; SB; \
  PRIO1; MFMA16(0); PRIO0; SB; BARR; SB; \
  /* p3 */ \
  LOAD_A(P,1,1); \
  ISSUE_B(tn2_, 0, 0); \
  VMW(6); SB; \
  CVT_WRITE(1, Pn, 1); \
  SB; BARR; LGK; SB; \
  PRIO1; MFMA16(1); PRIO0; SB; BARR; SB; }

#define K_LOOP(NT_) { \
  STAGE_A(0,0,0); STAGE_A(0,1,0); \
  ISSUE_B(0,0,0); ISSUE_B(0,1,1); \
  VMW(0); SB; \
  CVT_WRITE(0,0,0); CVT_WRITE(1,0,1); \
  STAGE_A(1,0,1); \
  ISSUE_B(1,0,0); \
  LGK; SB; BARR; SB; \
  _Pragma("unroll 1") \
  for (int tt = 0; tt < (NT_)/2; ++tt) { \
    TILE_PHASES(2*tt,   0, 1, NT_); \
    TILE_PHASES(2*tt+1, 1, 0, NT_); \
  } }

// ---------------- gate+up: 256 tokens x (128 I-cols x {g,u}), fp32 weights ----------------
__global__ __launch_bounds__(512, 2)
void gu8_kernel(const unsigned short* __restrict__ xb,
                const float* __restrict__ wg,
                const float* __restrict__ wu,
                const int* __restrict__ tb, const int* __restrict__ ntb,
                const int* __restrict__ offs, const int* __restrict__ perm,
                unsigned short* __restrict__ H)
{
  __shared__ unsigned short smem[65536];   // 128 KB

  int nwg = gridDim.x * gridDim.y;
  int lid = blockIdx.y * gridDim.x + blockIdx.x;
  int cpx = nwg >> 3;
  int sid = (lid & 7) * cpx + (lid >> 3);
  int bx = sid % gridDim.x;
  int by = sid / gridDim.x;
  if (bx >= *ntb) return;
  int ent = tb[bx];
  int e = ent >> 16, rb = ent & 0xffff;
  int slotbase = offs[e] + rb * 256;
  int i0 = by * 128;

  int tid = threadIdx.x, lane = tid & 63, w = tid >> 6;
  int wr = w >> 2, wc = w & 3;

  // staging lane constants (pre-swizzled source mapping)
  int cS = (lane & 7) ^ (lane >> 3);
  int rrS = 2 * (lane >> 3) + (cS >> 2);
  int kcS = (cS & 3) * 8;
  int ar0 = (w * 2 + 0) * 16 + rrS;
  int tk0 = perm[slotbase + ar0];       if (tk0 < 0) tk0 = 0;
  int tk1 = perm[slotbase + ar0 + 16];  if (tk1 < 0) tk1 = 0;
  const unsigned short* aptr0 = xb + (size_t)tk0 * D_ + kcS;
  const unsigned short* aptr1 = xb + (size_t)tk1 * D_ + kcS;
  // B fp32 sources: j=0 gate, j=1 up (same I-row)
  const float* bsrc0 = wg + ((size_t)e * I_ + i0 + w * 16 + rrS) * D_ + kcS;
  const float* bsrc1 = wu + ((size_t)e * I_ + i0 + w * 16 + rrS) * D_ + kcS;

  // read lane constants
  int hl = (lane & 15) >> 1;
  int pA = (((lane & 1) * 4 + (lane >> 4)) ^ hl) * 8;
  int aBase = wr * 4096 + hl * 64 + pA;
  int bBase = wc * 2048 + hl * 64 + pA;

  s8v af[4], bf[4];
  float4 xq[2][4];
  f32x4 acc[8][4];
#pragma unroll
  for (int m = 0; m < 8; m++)
#pragma unroll
    for (int n = 0; n < 4; n++) acc[m][n] = f32x4{0.f,0.f,0.f,0.f};

  K_LOOP(32);   // D_/64

  // epilogue: h = silu(g)*u ; acc[m][2p] = gate, acc[m][2p+1] = up
#pragma unroll
  for (int m = 0; m < 8; m++) {
#pragma unroll
    for (int r = 0; r < 4; r++) {
      int row = wr * 128 + m * 16 + (lane >> 4) * 4 + r;
      size_t hbase = (size_t)(slotbase + row) * I_ + i0 + (lane & 15);
#pragma unroll
      for (int pr = 0; pr < 2; pr++) {
        float g = acc[m][pr*2][r];
        float u = acc[m][pr*2+1][r];
        float h = (g / (1.0f + __expf(-g))) * u;
        H[hbase + (wc * 2 + pr) * 16] = f2bf(h);
      }
    }
  }
}

// ---------------- down: 256 slots x 256 D-cols, fp32 weights, weighted scatter ----------------
__global__ __launch_bounds__(512, 2)
void down8_kernel(const unsigned short* __restrict__ H,
                  const float* __restrict__ wd,
                  const int* __restrict__ tb, const int* __restrict__ ntb,
                  const int* __restrict__ offs, const int* __restrict__ perm,
                  const float* __restrict__ wgt,
                  float* __restrict__ out)
{
  __shared__ unsigned short smem[65536];

  int nwg = gridDim.x * gridDim.y;
  int lid = blockIdx.y * gridDim.x + blockIdx.x;
  int cpx = nwg >> 3;
  int sid = (lid & 7) * cpx + (lid >> 3);
  int bx = sid % gridDim.x;
  int by = sid / gridDim.x;
  if (bx >= *ntb) return;
  int ent = tb[bx];
  int e = ent >> 16, rb = ent & 0xffff;
  int slotbase = offs[e] + rb * 256;
  int d0 = by * 256;

  int tid = threadIdx.x, lane = tid & 63, w = tid >> 6;
  int wr = w >> 2, wc = w & 3;

  int cS = (lane & 7) ^ (lane >> 3);
  int rrS = 2 * (lane >> 3) + (cS >> 2);
  int kcS = (cS & 3) * 8;
  int ar0 = (w * 2 + 0) * 16 + rrS;
  const unsigned short* aptr0 = H + (size_t)(slotbase + ar0) * I_ + kcS;
  const unsigned short* aptr1 = H + (size_t)(slotbase + ar0 + 16) * I_ + kcS;
  const float* bsrc0 = wd + ((size_t)e * D_ + d0 + (w*2+0)*16 + rrS) * I_ + kcS;
  const float* bsrc1 = wd + ((size_t)e * D_ + d0 + (w*2+1)*16 + rrS) * I_ + kcS;

  int hl = (lane & 15) >> 1;
  int pA = (((lane & 1) * 4 + (lane >> 4)) ^ hl) * 8;
  int aBase = wr * 4096 + hl * 64 + pA;
  int bBase = wc * 2048 + hl * 64 + pA;

  s8v af[4], bf[4];
  float4 xq[2][4];
  f32x4 acc[8][4];
#pragma unroll
  for (int m = 0; m < 8; m++)
#pragma unroll
    for (int n = 0; n < 4; n++) acc[m][n] = f32x4{0.f,0.f,0.f,0.f};

  K_LOOP(64);   // I_/64

#pragma unroll
  for (int m = 0; m < 8; m++) {
#pragma unroll
    for (int r = 0; r < 4; r++) {
      int row = wr * 128 + m * 16 + (lane >> 4) * 4 + r;
      int s = slotbase + row;
      int tok = perm[s];
      if (tok < 0) continue;
      float wv = wgt[s];
      float* op = out + (size_t)tok * D_ + d0 + wc * 64 + (lane & 15);
#pragma unroll
      for (int n = 0; n < 4; n++)
        atomicAdd(op + n * 16, acc[m][n][r] * wv);
    }
  }
}

extern "C" void kernel_launch(void* const* d_in, const int* in_sizes, int n_in,
                              void* d_out, int out_size, void* d_ws, size_t ws_size,
                              hipStream_t stream)
{
  const float* x  = (const float*)d_in[0];
  const float* ew = (const float*)d_in[1];
  const int*  idx = (const int*)d_in[2];
  const float* wg = (const float*)d_in[4];
  const float* wu = (const float*)d_in[5];
  const float* wd = (const float*)d_in[6];
  float* out = (float*)d_out;

  char* ws = (char*)d_ws;
  int* cnt   = (int*)(ws);
  int* ntb   = (int*)(ws + 64);
  int* tb    = (int*)(ws + 128);
  int* offs  = (int*)(ws + 640);
  int* perm  = (int*)(ws + 4096);
  float* wgt = (float*)(ws + 4096 + PADMAX * 4);

  const size_t xb_off = 131072;
  const size_t xb_b   = (size_t)N_ * D_ * 2;      // 16.78 MB
  unsigned short* xb = (unsigned short*)(ws + xb_off);
  unsigned short* H  = (unsigned short*)(ws + xb_off + xb_b);
  // ws need: 131072 + 16.78 MB + 83.9 MB ~= 101 MB

  hipMemsetAsync(d_out, 0, (size_t)N_ * D_ * sizeof(float), stream);
  route_kernel<<<1, 256, 0, stream>>>(idx, ew, 256, cnt, offs, tb, ntb, perm, wgt);
  cvt8_kernel<<<(N_ * D_ / 8) / 256, 256, 0, stream>>>(x, xb);
  gu8_kernel<<<dim3(MAXTB256, I_ / 128), 512, 0, stream>>>(xb, wg, wu, tb, ntb, offs, perm, H);
  down8_kernel<<<dim3(MAXTB256, D_ / 256), 512, 0, stream>>>(H, wd, tb, ntb, offs, perm, wgt, out);
}

// Round 6
// 837.938 us; speedup vs baseline: 1.2253x; 1.2253x over previous
//
#include <hip/hip_runtime.h>
#include <hip/hip_bf16.h>
#include <math.h>

// Problem constants
#define E_ 8
#define D_ 2048
#define I_ 4096
#define TOPK_ 2
#define N_ 4096
#define NPAIR (N_*TOPK_)
#define PADMAX 10240
#define MAXTB256 40
#define NIB 16           // GEMM by-rows per gu8 half (I/2 / 128)
#define CVTX 13          // extra bx columns carrying converter blocks
#define CH_X   (1L<<20)  // x chunks (8 elems each)
#define CH_HALF (1L<<22) // per-matrix half-I chunks
#define CH_WD  (1L<<23)  // full wd chunks

typedef __attribute__((ext_vector_type(8))) short s8v;
typedef __attribute__((ext_vector_type(8))) unsigned short us8;
typedef __attribute__((ext_vector_type(4))) float f32x4;
typedef const __attribute__((address_space(1))) void* gvp;
typedef __attribute__((address_space(3))) void* lvp;

__device__ __forceinline__ unsigned short f2bf(float f) {
  union { float f; unsigned int u; } c; c.f = f;
  unsigned int u = c.u;
  u += 0x7fffu + ((u >> 16) & 1u);
  return (unsigned short)(u >> 16);
}

__device__ __forceinline__ void cvt_chunk(const float* __restrict__ src,
                                          unsigned short* __restrict__ dst,
                                          size_t off) {
  float4 a = *(const float4*)(src + off);
  float4 b = *(const float4*)(src + off + 4);
  us8 o;
  o[0]=f2bf(a.x); o[1]=f2bf(a.y); o[2]=f2bf(a.z); o[3]=f2bf(a.w);
  o[4]=f2bf(b.x); o[5]=f2bf(b.y); o[6]=f2bf(b.z); o[7]=f2bf(b.w);
  *(us8*)(dst + off) = o;
}

// convert chunk of an I-half region of a [E][I][D] matrix (ihalf = 0/1)
__device__ __forceinline__ void cvt_half(const float* __restrict__ src,
                                         unsigned short* __restrict__ dst,
                                         long chunk, int ihalf) {
  long f = chunk << 3;
  int e = (int)(f >> 22);
  long r = f & ((1L << 22) - 1);
  size_t off = ((size_t)e << 23) + ((size_t)ihalf << 22) + (size_t)r;
  cvt_chunk(src, dst, off);
}

// ---------------- Head: route (block 0) + x cvt + wg/wu half0 cvt ----------------
__global__ __launch_bounds__(512)
void head_kernel(const int* __restrict__ idx, const float* __restrict__ ew,
                 int* cnt, int* offs, int* tb, int* ntb,
                 int* perm, float* wgt,
                 const float* __restrict__ x, unsigned short* __restrict__ xb,
                 const float* __restrict__ wg, unsigned short* __restrict__ wgb,
                 const float* __restrict__ wu, unsigned short* __restrict__ wub)
{
  if (blockIdx.x == 0) {
    // routing (pad = 256)
    __shared__ int scnt[E_], soff[E_ + 1], scur[E_];
    int t = threadIdx.x;
    if (t < E_) scnt[t] = 0;
    __syncthreads();
    for (int p = t; p < NPAIR; p += blockDim.x) atomicAdd(&scnt[idx[p]], 1);
    __syncthreads();
    if (t == 0) {
      int o = 0;
      for (int e = 0; e < E_; e++) {
        soff[e] = o; scur[e] = o;
        o += ((scnt[e] + 255) / 256) * 256;
      }
      soff[E_] = o;
      int T = 0;
      for (int e = 0; e < E_; e++) {
        int nb = (scnt[e] + 255) / 256;
        for (int rb = 0; rb < nb; rb++) tb[T++] = (e << 16) | rb;
      }
      *ntb = T;
      for (int e = 0; e < E_; e++) { cnt[e] = scnt[e]; offs[e] = soff[e]; }
      offs[E_] = o;
    }
    __syncthreads();
    for (int e = 0; e < E_; e++) {
      int start = soff[e] + scnt[e], end = soff[e + 1];
      for (int s = start + t; s < end; s += blockDim.x) { perm[s] = -1; wgt[s] = 0.f; }
    }
    __syncthreads();
    for (int p = t; p < NPAIR; p += blockDim.x) {
      int e = idx[p];
      int pos = atomicAdd(&scur[e], 1);
      perm[pos] = p / TOPK_;
      wgt[pos]  = ew[p];
    }
    return;
  }
  // conversion blocks
  const long TOTAL = CH_X + 2 * CH_HALF;
  long c0 = (long)(blockIdx.x - 1) * 512 + threadIdx.x;
  long stride = (long)(gridDim.x - 1) * 512;
  for (long c = c0; c < TOTAL; c += stride) {
    if (c < CH_X) cvt_chunk(x, xb, (size_t)c << 3);
    else if (c < CH_X + CH_HALF) cvt_half(wg, wgb, c - CH_X, 0);
    else cvt_half(wu, wub, c - CH_X - CH_HALF, 0);
  }
}

// =================== 8-phase 256-tile grouped GEMM machinery (round-3 proven) ===================
// LDS: smem[65536] ushort = 128 KB. A slabs [2buf][2kh][128vrow][64elem] at 0,
// B slabs same at 32768. vrow v packs rows 2v,2v+1; 16B-chunk at position
// p = c ^ (v&7), logical chunk c = (r&1)*4 + kc.
#define A_SLAB(P,KH) (((P)*2+(KH))*8192)
#define B_SLAB(P,KH) (32768 + ((P)*2+(KH))*8192)

#define SB  __builtin_amdgcn_sched_barrier(0)
#define BARR __builtin_amdgcn_s_barrier()
#define VMW(N) asm volatile("s_waitcnt vmcnt(" #N ")" ::: "memory")
#define LGK asm volatile("s_waitcnt lgkmcnt(0)" ::: "memory")
#define PRIO1 __builtin_amdgcn_s_setprio(1)
#define PRIO0 __builtin_amdgcn_s_setprio(0)

#define LOAD_A(P,KH,MH) { \
  const unsigned short* ap_ = &smem[A_SLAB(P,KH) + aBase + (MH)*2048]; \
  af[0] = *(const s8v*)(ap_);      af[1] = *(const s8v*)(ap_+512); \
  af[2] = *(const s8v*)(ap_+1024); af[3] = *(const s8v*)(ap_+1536); }

#define LOAD_B(P,KH) { \
  const unsigned short* bp_ = &smem[B_SLAB(P,KH) + bBase]; \
  bf[0] = *(const s8v*)(bp_);      bf[1] = *(const s8v*)(bp_+512); \
  bf[2] = *(const s8v*)(bp_+1024); bf[3] = *(const s8v*)(bp_+1536); }

#define STAGE_A(T,KH,P) { \
  __builtin_amdgcn_global_load_lds((gvp)(aptr0 + (T)*64 + (KH)*32), (lvp)(&smem[A_SLAB(P,KH) + (w*2+0)*512]), 16, 0, 0); \
  __builtin_amdgcn_global_load_lds((gvp)(aptr1 + (T)*64 + (KH)*32), (lvp)(&smem[A_SLAB(P,KH) + (w*2+1)*512]), 16, 0, 0); }

#define STAGE_B(T,KH,P) { \
  __builtin_amdgcn_global_load_lds((gvp)(bptr0 + (T)*64 + (KH)*32), (lvp)(&smem[B_SLAB(P,KH) + (w*2+0)*512]), 16, 0, 0); \
  __builtin_amdgcn_global_load_lds((gvp)(bptr1 + (T)*64 + (KH)*32), (lvp)(&smem[B_SLAB(P,KH) + (w*2+1)*512]), 16, 0, 0); }

#define MFMA16(MH) { \
  _Pragma("unroll") for (int m_ = 0; m_ < 4; m_++) \
    _Pragma("unroll") for (int n_ = 0; n_ < 4; n_++) \
      acc[(MH)*4+m_][n_] = __builtin_amdgcn_mfma_f32_16x16x32_bf16(af[m_], bf[n_], acc[(MH)*4+m_][n_], 0, 0, 0); }

#define TILE_PHASES(T, P, Pn, NT_) { \
  if (T) { VMW(4); SB; } \
  LOAD_B(P, 0); LOAD_A(P, 0, 0); \
  if ((T) + 1 < (NT_)) { STAGE_A((T)+1, 1, Pn); } \
  SB; BARR; LGK; SB; \
  PRIO1; MFMA16(0); PRIO0; SB; BARR; SB; \
  LOAD_A(P, 0, 1); \
  if ((T) + 1 < (NT_)) { STAGE_B((T)+1, 1, Pn); } \
  SB; BARR; LGK; SB; \
  PRIO1; MFMA16(1); PRIO0; SB; BARR; SB; \
  if ((T) == (NT_) - 1) { VMW(0); SB; } else { VMW(4); SB; } \
  LOAD_B(P, 1); LOAD_A(P, 1, 0); \
  if ((T) + 2 < (NT_)) { STAGE_A((T)+2, 0, P); } \
  SB; BARR; LGK; SB; \
  PRIO1; MFMA16(0); PRIO0; SB; BARR; SB; \
  LOAD_A(P, 1, 1); \
  if ((T) + 2 < (NT_)) { STAGE_B((T)+2, 0, P); } \
  SB; BARR; LGK; SB; \
  PRIO1; MFMA16(1); PRIO0; SB; BARR; SB; }

#define K_LOOP(NT_) { \
  STAGE_A(0,0,0); STAGE_B(0,0,0); STAGE_A(0,1,0); STAGE_B(0,1,0); \
  STAGE_A(1,0,1); STAGE_B(1,0,1); \
  VMW(8); SB; BARR; SB; \
  _Pragma("unroll 1") \
  for (int tt = 0; tt < (NT_)/2; ++tt) { \
    TILE_PHASES(2*tt,   0, 1, NT_); \
    TILE_PHASES(2*tt+1, 1, 0, NT_); \
  } }

// ---------------- gate+up half-I GEMM + appended converter blocks ----------------
// GEMM blocks: bx < 40, by < 16, i0 = i_base + by*128. Converter blocks: bx >= 40.
// cvt_mode 1: {cs0->cd0, cs1->cd1} I-half-1 regions; 2: cs0->cd0 flat (wd).
__global__ __launch_bounds__(512, 2)
void gu8_kernel(const unsigned short* __restrict__ xb,
                const unsigned short* __restrict__ wgb,
                const unsigned short* __restrict__ wub,
                const int* __restrict__ tb, const int* __restrict__ ntb,
                const int* __restrict__ offs, const int* __restrict__ perm,
                unsigned short* __restrict__ H,
                int i_base, int cvt_mode,
                const float* __restrict__ cs0, unsigned short* __restrict__ cd0,
                const float* __restrict__ cs1, unsigned short* __restrict__ cd1)
{
  __shared__ unsigned short smem[65536];   // 128 KB

  if (blockIdx.x >= MAXTB256) {
    // converter block
    long cid = (long)(blockIdx.x - MAXTB256) + (long)CVTX * blockIdx.y;
    long c0 = cid * 512 + threadIdx.x;
    long stride = (long)CVTX * NIB * 512;
    if (cvt_mode == 1) {
      for (long c = c0; c < 2 * CH_HALF; c += stride) {
        if (c < CH_HALF) cvt_half(cs0, cd0, c, 1);
        else cvt_half(cs1, cd1, c - CH_HALF, 1);
      }
    } else {
      for (long c = c0; c < CH_WD; c += stride) cvt_chunk(cs0, cd0, (size_t)c << 3);
    }
    return;
  }

  // XCD-chunked swizzle over the 40x16 GEMM subgrid
  int lid = blockIdx.y * MAXTB256 + blockIdx.x;
  int sid = (lid & 7) * (MAXTB256 * NIB / 8) + (lid >> 3);
  int bx = sid % MAXTB256;
  int by = sid / MAXTB256;
  if (bx >= *ntb) return;
  int ent = tb[bx];
  int e = ent >> 16, rb = ent & 0xffff;
  int slotbase = offs[e] + rb * 256;
  int i0 = i_base + by * 128;

  int tid = threadIdx.x, lane = tid & 63, w = tid >> 6;
  int wr = w >> 2, wc = w & 3;

  // staging lane constants (pre-swizzled source mapping)
  int cS = (lane & 7) ^ (lane >> 3);
  int rrS = 2 * (lane >> 3) + (cS >> 2);
  int kcS = (cS & 3) * 8;
  int ar0 = (w * 2 + 0) * 16 + rrS;
  int tk0 = perm[slotbase + ar0];       if (tk0 < 0) tk0 = 0;
  int tk1 = perm[slotbase + ar0 + 16];  if (tk1 < 0) tk1 = 0;
  const unsigned short* aptr0 = xb + (size_t)tk0 * D_ + kcS;
  const unsigned short* aptr1 = xb + (size_t)tk1 * D_ + kcS;
  const unsigned short* bptr0 = wgb + ((size_t)e * I_ + i0 + w * 16 + rrS) * D_ + kcS;
  const unsigned short* bptr1 = wub + ((size_t)e * I_ + i0 + w * 16 + rrS) * D_ + kcS;

  // read lane constants
  int hl = (lane & 15) >> 1;
  int pA = (((lane & 1) * 4 + (lane >> 4)) ^ hl) * 8;
  int aBase = wr * 4096 + hl * 64 + pA;
  int bBase = wc * 2048 + hl * 64 + pA;

  s8v af[4], bf[4];
  f32x4 acc[8][4];
#pragma unroll
  for (int m = 0; m < 8; m++)
#pragma unroll
    for (int n = 0; n < 4; n++) acc[m][n] = f32x4{0.f,0.f,0.f,0.f};

  K_LOOP(32);   // D_/64

  // epilogue: h = silu(g)*u ; acc[m][2p] = gate, acc[m][2p+1] = up
#pragma unroll
  for (int m = 0; m < 8; m++) {
#pragma unroll
    for (int r = 0; r < 4; r++) {
      int row = wr * 128 + m * 16 + (lane >> 4) * 4 + r;
      size_t hbase = (size_t)(slotbase + row) * I_ + i0 + (lane & 15);
#pragma unroll
      for (int pr = 0; pr < 2; pr++) {
        float g = acc[m][pr*2][r];
        float u = acc[m][pr*2+1][r];
        float h = (g / (1.0f + __expf(-g))) * u;
        H[hbase + (wc * 2 + pr) * 16] = f2bf(h);
      }
    }
  }
}

// ---------------- down: 256 slots x 256 D-cols, K-split x2, weighted scatter ----------------
__global__ __launch_bounds__(512, 2)
void down8_kernel(const unsigned short* __restrict__ H,
                  const unsigned short* __restrict__ wdb,
                  const int* __restrict__ tb, const int* __restrict__ ntb,
                  const int* __restrict__ offs, const int* __restrict__ perm,
                  const float* __restrict__ wgt,
                  float* __restrict__ out)
{
  __shared__ unsigned short smem[65536];

  int nwg = gridDim.x * gridDim.y * gridDim.z;
  int lid = (blockIdx.z * gridDim.y + blockIdx.y) * gridDim.x + blockIdx.x;
  int cpx = nwg >> 3;
  int sid = (lid & 7) * cpx + (lid >> 3);
  int bx = sid % gridDim.x;
  int rem = sid / gridDim.x;
  int by = rem % gridDim.y;
  int z  = rem / gridDim.y;
  if (bx >= *ntb) return;
  int ent = tb[bx];
  int e = ent >> 16, rb = ent & 0xffff;
  int slotbase = offs[e] + rb * 256;
  int d0 = by * 256;
  int kb = z * (I_ / 2);

  int tid = threadIdx.x, lane = tid & 63, w = tid >> 6;
  int wr = w >> 2, wc = w & 3;

  int cS = (lane & 7) ^ (lane >> 3);
  int rrS = 2 * (lane >> 3) + (cS >> 2);
  int kcS = (cS & 3) * 8;
  int ar0 = (w * 2 + 0) * 16 + rrS;
  const unsigned short* aptr0 = H + (size_t)(slotbase + ar0) * I_ + kcS + kb;
  const unsigned short* aptr1 = H + (size_t)(slotbase + ar0 + 16) * I_ + kcS + kb;
  const unsigned short* bptr0 = wdb + ((size_t)e * D_ + d0 + (w*2+0)*16 + rrS) * I_ + kcS + kb;
  const unsigned short* bptr1 = wdb + ((size_t)e * D_ + d0 + (w*2+1)*16 + rrS) * I_ + kcS + kb;

  int hl = (lane & 15) >> 1;
  int pA = (((lane & 1) * 4 + (lane >> 4)) ^ hl) * 8;
  int aBase = wr * 4096 + hl * 64 + pA;
  int bBase = wc * 2048 + hl * 64 + pA;

  s8v af[4], bf[4];
  f32x4 acc[8][4];
#pragma unroll
  for (int m = 0; m < 8; m++)
#pragma unroll
    for (int n = 0; n < 4; n++) acc[m][n] = f32x4{0.f,0.f,0.f,0.f};

  K_LOOP(32);   // (I_/2)/64

#pragma unroll
  for (int m = 0; m < 8; m++) {
#pragma unroll
    for (int r = 0; r < 4; r++) {
      int row = wr * 128 + m * 16 + (lane >> 4) * 4 + r;
      int s = slotbase + row;
      int tok = perm[s];
      if (tok < 0) continue;
      float wv = wgt[s];
      float* op = out + (size_t)tok * D_ + d0 + wc * 64 + (lane & 15);
#pragma unroll
      for (int n = 0; n < 4; n++)
        atomicAdd(op + n * 16, acc[m][n][r] * wv);
    }
  }
}

extern "C" void kernel_launch(void* const* d_in, const int* in_sizes, int n_in,
                              void* d_out, int out_size, void* d_ws, size_t ws_size,
                              hipStream_t stream)
{
  const float* x  = (const float*)d_in[0];
  const float* ew = (const float*)d_in[1];
  const int*  idx = (const int*)d_in[2];
  const float* wg = (const float*)d_in[4];
  const float* wu = (const float*)d_in[5];
  const float* wd = (const float*)d_in[6];
  float* out = (float*)d_out;

  char* ws = (char*)d_ws;
  int* cnt   = (int*)(ws);
  int* ntb   = (int*)(ws + 64);
  int* tb    = (int*)(ws + 128);
  int* offs  = (int*)(ws + 640);
  int* perm  = (int*)(ws + 4096);
  float* wgt = (float*)(ws + 4096 + PADMAX * 4);

  const size_t xb_off = 131072;
  const size_t xb_b   = (size_t)N_ * D_ * 2;         // 16.78 MB
  const size_t H_b    = (size_t)PADMAX * I_ * 2;     // 83.9 MB
  const size_t w_b    = (size_t)E_ * I_ * D_ * 2;    // 134.2 MB each
  unsigned short* xb  = (unsigned short*)(ws + xb_off);
  unsigned short* H   = (unsigned short*)(ws + xb_off + xb_b);
  unsigned short* wgb = (unsigned short*)(ws + xb_off + xb_b + H_b);
  unsigned short* wub = (unsigned short*)((char*)wgb + w_b);
  unsigned short* wdb = (unsigned short*)((char*)wub + w_b);
  // ws need ~503 MB (verified available in rounds 2-3)

  hipMemsetAsync(d_out, 0, (size_t)N_ * D_ * sizeof(float), stream);
  // K1: route + x cvt + wg/wu half0 cvt
  head_kernel<<<2048, 512, 0, stream>>>(idx, ew, cnt, offs, tb, ntb, perm, wgt,
                                        x, xb, wg, wgb, wu, wub);
  // K2: gate/up GEMM on I-half0, converts wg/wu half1 on the side
  gu8_kernel<<<dim3(MAXTB256 + CVTX, NIB), 512, 0, stream>>>(
      xb, wgb, wub, tb, ntb, offs, perm, H, 0, 1, wg, wgb, wu, wub);
  // K3: gate/up GEMM on I-half1, converts wd on the side
  gu8_kernel<<<dim3(MAXTB256 + CVTX, NIB), 512, 0, stream>>>(
      xb, wgb, wub, tb, ntb, offs, perm, H, I_ / 2, 2, wd, wdb, (const float*)0, (unsigned short*)0);
  // K4: down GEMM, K-split x2
  down8_kernel<<<dim3(MAXTB256, D_ / 256, 2), 512, 0, stream>>>(
      H, wdb, tb, ntb, offs, perm, wgt, out);
}